// Round 5
// baseline (436.046 us; speedup 1.0000x reference)
//
#include <hip/hip_runtime.h>
#include <hip/hip_bf16.h>
#include <stdint.h>

// Problem constants
constexpr int Bc = 8, Sc = 2048, Ec = 1024, Hc = 64;

typedef __bf16 bf16x8 __attribute__((ext_vector_type(8)));
typedef float f32x4 __attribute__((ext_vector_type(4)));
typedef unsigned short ushort8 __attribute__((ext_vector_type(8)));
typedef unsigned short ushort4v __attribute__((ext_vector_type(4)));
typedef uint32_t uint32x4 __attribute__((ext_vector_type(4)));

static __device__ __forceinline__ unsigned short f2bf(float f) {
  uint32_t u = __builtin_bit_cast(uint32_t, f);
  u = u + 0x7fffu + ((u >> 16) & 1u);   // round-to-nearest-even
  return (unsigned short)(u >> 16);
}
static __device__ __forceinline__ bf16x8 ldb8(const unsigned short* p) {
  return __builtin_bit_cast(bf16x8, *(const ushort8*)p);
}
static __device__ __forceinline__ uint32_t pk2bf(float a, float b) {
  return (uint32_t)f2bf(a) | ((uint32_t)f2bf(b) << 16);
}

#define GLOBAL_LOAD_LDS16(g, l)                                              \
  __builtin_amdgcn_global_load_lds(                                          \
      (const __attribute__((address_space(1))) void*)(g),                    \
      (__attribute__((address_space(3))) void*)(l), 16, 0, 0)

// ---------------------------------------------------------------------------
// Kernel 0: W [E,H] fp32 -> Wt [3][H][E] bf16. Wq pre-scaled by 1/sqrt(H)=0.125
// (exact exponent shift in bf16) so attn needs no per-element scale.
// ---------------------------------------------------------------------------
__global__ __launch_bounds__(256) void wt_kernel(
    const float* __restrict__ Wq, const float* __restrict__ Wk,
    const float* __restrict__ Wv, unsigned short* __restrict__ Wt) {
  int idx = blockIdx.x * 256 + threadIdx.x;        // 0 .. 3*64*1024
  int m = idx >> 16;                                // /65536
  int r = idx & 65535;
  int h = r >> 10;
  int e = r & 1023;
  const float* W = (m == 0) ? Wq : (m == 1) ? Wk : Wv;
  float scale = (m == 0) ? 0.125f : 1.0f;
  Wt[idx] = f2bf(W[e * Hc + h] * scale);
}

// ---------------------------------------------------------------------------
// Kernel 0b: mask int32 [B,S,S] -> bitmask Mb [B][S][S/32] uint32.
// ---------------------------------------------------------------------------
__global__ __launch_bounds__(256) void mask_kernel(
    const int* __restrict__ mask, uint32_t* __restrict__ Mb) {
  int w = blockIdx.x * 256 + threadIdx.x;          // word index, B*S*64 total
  const int* src = mask + (size_t)w * 32;
  uint32_t bits = 0;
#pragma unroll
  for (int i = 0; i < 8; i++) {
    int4 v = *(const int4*)(src + i * 4);
    bits |= (v.x ? 1u : 0u) << (i * 4 + 0);
    bits |= (v.y ? 1u : 0u) << (i * 4 + 1);
    bits |= (v.z ? 1u : 0u) << (i * 4 + 2);
    bits |= (v.w ? 1u : 0u) << (i * 4 + 3);
  }
  Mb[w] = bits;
}

// ---------------------------------------------------------------------------
// Kernel 1: projections — DMA-staged (global_load_lds) double-buffered GEMM.
// Theory: prior rounds were load-queue-depth-bound (compiler sinks register-
// destination loads; ~3 KB/wave in flight -> ~1-2 TB/s by Little's law).
// global_load_lds has no dest regs: issue depth is structural (8 KB/wave).
// Block = 4 waves, owns 4 consecutive 16-row slabs (256 KB sequential).
// Each slab staged fp32 as two 32 KB K-halves into LDS bufs 0/1 (64 KB),
// 2-deep pipeline, counted vmcnt(8) + raw s_barrier (never vmcnt(0) in
// steady state). LDS dest linear; bank-conflict fix via pre-swizzled global
// source granule (lane ^ row&7) + same XOR on the read side.
// Waves split N: wave w owns output cols [16w,16w+16), full K -> no combine.
// Q,K stored row-major [s][h]; V stored transposed [b][h][s].
// ---------------------------------------------------------------------------
__global__ __launch_bounds__(256, 2) void proj_kernel(
    const float* __restrict__ Xq, const float* __restrict__ Xk,
    const float* __restrict__ Xv, const float* __restrict__ bq,
    const float* __restrict__ bk, const float* __restrict__ bv,
    const unsigned short* __restrict__ Wt,
    unsigned short* __restrict__ Qb, unsigned short* __restrict__ Kb,
    unsigned short* __restrict__ Vt) {
  const int mat = blockIdx.y;
  const float* X = (mat == 0) ? Xq : (mat == 1) ? Xk : Xv;
  const float* bias = (mat == 0) ? bq : (mat == 1) ? bk : bv;
  const float bscale = (mat == 0) ? 0.125f : 1.0f;
  const unsigned short* W = Wt + mat * (Hc * Ec);

  const int tid = threadIdx.x;
  const int wave = tid >> 6, lane = tid & 63;
  const int rl = lane & 15, kg = lane >> 4;

  __shared__ __align__(16) char smem[65536];   // 2 x 32 KB fp32 half-slab bufs

  const char* xb = (const char*)X + (size_t)blockIdx.x * 262144;  // 4 slabs
  const unsigned short* wp_base = W + (size_t)(wave * 16 + rl) * Ec + kg * 8;
  const float bcol = bias[wave * 16 + rl] * bscale;

  // stage one 32 KB half-slab: wave w DMAs rows [4w,4w+4), 2x1KB per row.
  // LDS layout: [16 rows][2048 B] linear; global granule pre-swizzled so the
  // read-side XOR ((rl&7)<<4) sees correct data (involution both sides).
  auto stage = [&](int slab, int half, int buf) {
#pragma unroll
    for (int j = 0; j < 8; j++) {
      int row = wave * 4 + (j >> 1);
      int part = j & 1;
      const char* src = xb + (size_t)slab * 65536 + row * 4096 + half * 2048 +
                        part * 1024 + ((lane ^ (row & 7)) * 16);
      char* dst = smem + buf * 32768 + row * 2048 + part * 1024;
      GLOBAL_LOAD_LDS16(src, dst);
    }
  };

  // compute one half-slab: M16 (slab rows) x N16 (wave's cols) x K512
  auto compute = [&](int half, int buf, f32x4& acc) {
    const char* lb = smem + buf * 32768;
    const unsigned short* wp = wp_base + half * 512;
    const uint32_t sw = (uint32_t)((rl & 7) << 4);
#pragma unroll
    for (int c = 0; c < 16; c++) {
      uint32_t boff = (uint32_t)(kg * 32 + c * 128);
      float4 x0 = *(const float4*)(lb + rl * 2048 + (boff ^ sw));
      float4 x1 = *(const float4*)(lb + rl * 2048 + ((boff + 16) ^ sw));
      ushort8 wv = *(const ushort8*)(wp + c * 32);
      uint32x4 u = (uint32x4){pk2bf(x0.x, x0.y), pk2bf(x0.z, x0.w),
                              pk2bf(x1.x, x1.y), pk2bf(x1.z, x1.w)};
      acc = __builtin_amdgcn_mfma_f32_16x16x32_bf16(
          __builtin_bit_cast(bf16x8, u), __builtin_bit_cast(bf16x8, wv), acc,
          0, 0, 0);
    }
  };

  stage(0, 0, 0);
  stage(0, 1, 1);

#pragma unroll 1
  for (int sl = 0; sl < 4; sl++) {
    f32x4 acc = (f32x4){0.f, 0.f, 0.f, 0.f};

    // even step: buf0 = (sl, half 0)
    asm volatile("s_waitcnt vmcnt(8)" ::: "memory");
    __builtin_amdgcn_sched_barrier(0);
    __builtin_amdgcn_s_barrier();
    compute(0, 0, acc);
    asm volatile("s_waitcnt lgkmcnt(0)" ::: "memory");
    __builtin_amdgcn_sched_barrier(0);
    __builtin_amdgcn_s_barrier();
    if (sl < 3) stage(sl + 1, 0, 0);

    // odd step: buf1 = (sl, half 1)
    if (sl < 3)
      asm volatile("s_waitcnt vmcnt(8)" ::: "memory");
    else
      asm volatile("s_waitcnt vmcnt(0)" ::: "memory");
    __builtin_amdgcn_sched_barrier(0);
    __builtin_amdgcn_s_barrier();
    compute(1, 1, acc);

    // epilogue for this slab (regs only; issued before next DMA batch)
    {
      int rowg = blockIdx.x * 64 + sl * 16;
      if (mat < 2) {
        unsigned short* out = (mat == 0) ? Qb : Kb;
#pragma unroll
        for (int r = 0; r < 4; r++)
          out[(size_t)(rowg + kg * 4 + r) * Hc + wave * 16 + rl] =
              f2bf(acc[r] + bcol);
      } else {
        int bb = rowg >> 11;               // slab never straddles a batch
        int sloc = (rowg & 2047) + kg * 4;
        ushort4v o;
#pragma unroll
        for (int r = 0; r < 4; r++) o[r] = f2bf(acc[r] + bcol);
        *(ushort4v*)(Vt + ((size_t)bb * Hc + wave * 16 + rl) * Sc + sloc) = o;
      }
    }

    asm volatile("s_waitcnt lgkmcnt(0)" ::: "memory");
    __builtin_amdgcn_sched_barrier(0);
    __builtin_amdgcn_s_barrier();
    if (sl < 3) stage(sl + 1, 1, 1);
  }
}

// ---------------------------------------------------------------------------
// Kernel 2: flash-style attention, faithful mask->1e-10 semantics.
// (UNCHANGED from round 4 for clean attribution.)
// ---------------------------------------------------------------------------
__global__ __launch_bounds__(256, 4) void attn_kernel(
    const unsigned short* __restrict__ Qb, const unsigned short* __restrict__ Kb,
    const unsigned short* __restrict__ Vt, const uint32_t* __restrict__ Mb,
    float* __restrict__ out) {
  const int id = blockIdx.x;
  const int b = id & 7;                 // XCD-swizzle: batch -> XCD
  const int q0 = (id >> 3) * 16;
  const int tid = threadIdx.x;
  const int wave = tid >> 6, lane = tid & 63;
  const int rl = lane & 15;

  __shared__ unsigned short Ps[4][16][72];  // per-wave P staging (no barrier)
  __shared__ float sm[4][16], sl[4][16];
  __shared__ float Os[4][16][64];

  const unsigned short* qptr =
      Qb + ((size_t)b * Sc + q0 + rl) * Hc + (lane >> 4) * 8;
  bf16x8 aQ0 = ldb8(qptr);
  bf16x8 aQ1 = ldb8(qptr + 32);

  float m_r[4], l_r[4];
  f32x4 Oacc[4];
#pragma unroll
  for (int r = 0; r < 4; r++) { m_r[r] = -INFINITY; l_r[r] = 0.f; }
#pragma unroll
  for (int ht = 0; ht < 4; ht++) Oacc[ht] = (f32x4){0.f, 0.f, 0.f, 0.f};

  const uint32_t* mbase[4];
#pragma unroll
  for (int r = 0; r < 4; r++)
    mbase[r] = Mb + ((size_t)b * Sc + q0 + (lane >> 4) * 4 + r) * 64;

  const unsigned short* kbase =
      Kb + ((size_t)b * Sc) * Hc + (size_t)rl * Hc + (lane >> 4) * 8;
  const unsigned short* vbase[4];
#pragma unroll
  for (int ht = 0; ht < 4; ht++)
    vbase[ht] = Vt + ((size_t)b * Hc + ht * 16 + rl) * Sc + (lane >> 4) * 8;

  const int kw = wave * 512;
  uint2 mva[4], mvb[4];   // bitmask double-buffer (2 words = 64 keys per row)

  auto issue_mask = [&](int koff, uint2 (&mv)[4]) {
#pragma unroll
    for (int r = 0; r < 4; r++)
      mv[r] = *(const uint2*)(mbase[r] + (koff >> 5));
  };
  auto compress = [&](const uint2 (&mv)[4]) -> uint32_t {
    uint32_t bits = 0;
#pragma unroll
    for (int r = 0; r < 4; r++) {
      bits |= ((mv[r].x >> rl) & 1u) << (0 + r);
      bits |= ((mv[r].x >> (16 + rl)) & 1u) << (4 + r);
      bits |= ((mv[r].y >> rl) & 1u) << (8 + r);
      bits |= ((mv[r].y >> (16 + rl)) & 1u) << (12 + r);
    }
    return bits;
  };

  auto process = [&](int koff, uint32_t bits) {
    float sv[4][4];
#pragma unroll
    for (int nt = 0; nt < 4; nt++) {
      const unsigned short* kp = kbase + (size_t)(koff + nt * 16) * Hc;
      bf16x8 bK0 = ldb8(kp);
      bf16x8 bK1 = ldb8(kp + 32);
      f32x4 s = (f32x4){0.f, 0.f, 0.f, 0.f};
      s = __builtin_amdgcn_mfma_f32_16x16x32_bf16(aQ0, bK0, s, 0, 0, 0);
      s = __builtin_amdgcn_mfma_f32_16x16x32_bf16(aQ1, bK1, s, 0, 0, 0);
#pragma unroll
      for (int r = 0; r < 4; r++)
        sv[nt][r] = ((bits >> (nt * 4 + r)) & 1u) ? 1e-10f : s[r];
    }

    float rmax[4];
#pragma unroll
    for (int r = 0; r < 4; r++) {
      rmax[r] = fmaxf(fmaxf(sv[0][r], sv[1][r]), fmaxf(sv[2][r], sv[3][r]));
#pragma unroll
      for (int off = 1; off < 16; off <<= 1)
        rmax[r] = fmaxf(rmax[r], __shfl_xor(rmax[r], off, 64));
    }

    float alpha[4], p[4][4], psum[4];
#pragma unroll
    for (int r = 0; r < 4; r++) {
      float mnew = fmaxf(m_r[r], rmax[r]);
      alpha[r] = __expf(m_r[r] - mnew);
      m_r[r] = mnew;
      psum[r] = 0.f;
    }
#pragma unroll
    for (int nt = 0; nt < 4; nt++)
#pragma unroll
      for (int r = 0; r < 4; r++) {
        p[nt][r] = __expf(sv[nt][r] - m_r[r]);
        psum[r] += p[nt][r];
      }
#pragma unroll
    for (int r = 0; r < 4; r++) {
#pragma unroll
      for (int off = 1; off < 16; off <<= 1)
        psum[r] += __shfl_xor(psum[r], off, 64);
      l_r[r] = l_r[r] * alpha[r] + psum[r];
    }
#pragma unroll
    for (int ht = 0; ht < 4; ht++)
#pragma unroll
      for (int r = 0; r < 4; r++) Oacc[ht][r] *= alpha[r];

#pragma unroll
    for (int nt = 0; nt < 4; nt++)
#pragma unroll
      for (int r = 0; r < 4; r++)
        Ps[wave][(lane >> 4) * 4 + r][nt * 16 + rl] = f2bf(p[nt][r]);

#pragma unroll
    for (int ks = 0; ks < 2; ks++) {
      bf16x8 aP = ldb8(&Ps[wave][rl][ks * 32 + (lane >> 4) * 8]);
#pragma unroll
      for (int ht = 0; ht < 4; ht++) {
        bf16x8 bV = ldb8(vbase[ht] + koff + ks * 32);
        Oacc[ht] = __builtin_amdgcn_mfma_f32_16x16x32_bf16(aP, bV, Oacc[ht], 0, 0, 0);
      }
    }
  };

  issue_mask(kw, mva);
  for (int c2 = 0; c2 < 8; c2 += 2) {
    issue_mask(kw + (c2 + 1) * 64, mvb);
    process(kw + c2 * 64, compress(mva));
    if (c2 + 2 < 8) issue_mask(kw + (c2 + 2) * 64, mva);
    process(kw + (c2 + 1) * 64, compress(mvb));
  }

  if (rl == 0) {
#pragma unroll
    for (int r = 0; r < 4; r++) {
      sm[wave][(lane >> 4) * 4 + r] = m_r[r];
      sl[wave][(lane >> 4) * 4 + r] = l_r[r];
    }
  }
  __syncthreads();

  float coef[4];
#pragma unroll
  for (int r = 0; r < 4; r++) {
    int row = (lane >> 4) * 4 + r;
    float M = fmaxf(fmaxf(sm[0][row], sm[1][row]), fmaxf(sm[2][row], sm[3][row]));
    coef[r] = __expf(m_r[r] - M);
  }
#pragma unroll
  for (int ht = 0; ht < 4; ht++)
#pragma unroll
    for (int r = 0; r < 4; r++)
      Os[wave][(lane >> 4) * 4 + r][ht * 16 + rl] = Oacc[ht][r] * coef[r];
  __syncthreads();

  {
#pragma unroll
    for (int i = 0; i < 4; i++) {
      int row = wave * 4 + i;
      float M = fmaxf(fmaxf(sm[0][row], sm[1][row]), fmaxf(sm[2][row], sm[3][row]));
      float L = sl[0][row] * __expf(sm[0][row] - M) +
                sl[1][row] * __expf(sm[1][row] - M) +
                sl[2][row] * __expf(sm[2][row] - M) +
                sl[3][row] * __expf(sm[3][row] - M);
      float acc = Os[0][row][lane] + Os[1][row][lane] +
                  Os[2][row][lane] + Os[3][row][lane];
      out[((size_t)b * Sc + q0 + row) * Hc + lane] = acc / L;
    }
  }
}

// ---------------------------------------------------------------------------
extern "C" void kernel_launch(void* const* d_in, const int* in_sizes, int n_in,
                              void* d_out, int out_size, void* d_ws, size_t ws_size,
                              hipStream_t stream) {
  const float* Xq = (const float*)d_in[0];
  const float* Xk = (const float*)d_in[1];
  const float* Xv = (const float*)d_in[2];
  const int* mask = (const int*)d_in[3];
  const float* Wq = (const float*)d_in[4];
  const float* bq = (const float*)d_in[5];
  const float* Wk = (const float*)d_in[6];
  const float* bk = (const float*)d_in[7];
  const float* Wv = (const float*)d_in[8];
  const float* bv = (const float*)d_in[9];

  unsigned short* Qb = (unsigned short*)d_ws;              // [16384][64] bf16
  unsigned short* Kb = Qb + (size_t)Bc * Sc * Hc;          // [16384][64] bf16
  unsigned short* Vt = Kb + (size_t)Bc * Sc * Hc;          // [8][64][2048] bf16
  unsigned short* Wt = Vt + (size_t)Bc * Sc * Hc;          // [3][64][1024] bf16
  uint32_t* Mb = (uint32_t*)(Wt + (size_t)3 * Hc * Ec);    // [8][2048][64] u32

  wt_kernel<<<dim3(3 * Hc * Ec / 256), 256, 0, stream>>>(Wq, Wk, Wv, Wt);
  mask_kernel<<<dim3(Bc * Sc * (Sc / 32) / 256), 256, 0, stream>>>(mask, Mb);
  proj_kernel<<<dim3(256, 3), 256, 0, stream>>>(Xq, Xk, Xv, bq, bk, bv,
                                                Wt, Qb, Kb, Vt);
  attn_kernel<<<dim3(Bc * Sc / 16), 256, 0, stream>>>(Qb, Kb, Vt, Mb,
                                                      (float*)d_out);
}